// Round 6
// baseline (394.222 us; speedup 1.0000x reference)
//
#include <hip/hip_runtime.h>

// Problem constants (fixed by reference): B=128, L=256, F=P=4, IN=1024, H=256, C=7
#define NN 32768        // N = B*L
#define INF 1024
#define HF 256

typedef __bf16 bf16x8 __attribute__((ext_vector_type(8)));
typedef float f32x4 __attribute__((ext_vector_type(4)));
typedef unsigned short u16x8 __attribute__((ext_vector_type(8)));

__device__ __forceinline__ float bf2f(unsigned short u) {
  union { unsigned int i; float f; } v; v.i = ((unsigned int)u) << 16; return v.f;
}
__device__ __forceinline__ unsigned short f2bf(float f) {
  union { float f; unsigned int i; } v; v.f = f;
  unsigned int x = v.i;
  return (unsigned short)((x + 0x7fffu + ((x >> 16) & 1u)) >> 16);  // RNE
}

// async global->LDS, 16B per lane; dest = lds base (wave-uniform) + lane*16
__device__ __forceinline__ void ld_lds16(const unsigned short* g, unsigned short* l) {
  __builtin_amdgcn_global_load_lds(
      (__attribute__((address_space(1))) const unsigned int*)g,
      (__attribute__((address_space(3))) unsigned int*)l, 16, 0, 0);
}

// ---- prep:
//  blocks [0,288):    weight repack via 64x64 LDS transpose (coalesced both sides)
//  blocks [288,2336): x fp32 -> bf16, grid-stride (16 float4/thread); loss zero in bid 288
// WbigT[n][k] (1024x1024) = [W0|W1|Wroot|Wskip]^T ; WsmT[n][k] (256x512) = [Wgrt;Wrel]^T
__global__ __launch_bounds__(256)
void diagcn_prep(const float* __restrict__ x, const float* __restrict__ Wrgcn,
                 const float* __restrict__ Wroot, const float* __restrict__ Wskip,
                 const float* __restrict__ Wgrt, const float* __restrict__ Wrel,
                 unsigned short* __restrict__ Xbf, unsigned short* __restrict__ WbigT,
                 unsigned short* __restrict__ WsmT, float* __restrict__ loss) {
  int bid = blockIdx.x;
  if (bid >= 288) {
    if (bid == 288 && threadIdx.x == 0) loss[0] = 0.f;
    int idx = (bid - 288) * 256 + threadIdx.x;
    const int stride = 2048 * 256;       // 524,288 threads
#pragma unroll
    for (int it = 0; it < 16; ++it, idx += stride) {
      float4 v = ((const float4*)x)[idx];
      ushort4 u; u.x = f2bf(v.x); u.y = f2bf(v.y); u.z = f2bf(v.z); u.w = f2bf(v.w);
      ((ushort4*)Xbf)[idx] = u;
    }
    return;
  }
  __shared__ float tile[64 * 65];
  int tb = bid;
  const float* src;
  int k0, ncol0;
  unsigned short* dst;
  int ldd, nrow0;
  if (tb < 256) {            // WbigT tiles: tn 0..15, tk 0..15
    int tn = tb >> 4, tk = tb & 15;
    int mat = tn >> 2;
    src = (mat == 0) ? Wrgcn : (mat == 1) ? (Wrgcn + 262144) : (mat == 2) ? Wroot : Wskip;
    k0 = tk * 64; ncol0 = (tn & 3) * 64;
    dst = WbigT; ldd = 1024; nrow0 = tn * 64;
  } else {                   // WsmT tiles: tn 0..3, tk 0..7
    int t2 = tb - 256;
    int tn = t2 >> 3, tk = t2 & 7;
    src = (tk < 4) ? Wgrt : Wrel;
    k0 = (tk & 3) * 64; ncol0 = tn * 64;
    dst = WsmT; ldd = 512; nrow0 = tn * 64;
  }
  int kdst0 = (tb < 256) ? k0 : (((tb - 256) & 7) * 64);
  int c = threadIdx.x & 63, rb = threadIdx.x >> 6;
#pragma unroll
  for (int it = 0; it < 16; ++it) {
    int r = rb + it * 4;
    tile[r * 65 + c] = src[(size_t)(k0 + r) * 256 + ncol0 + c];
  }
  __syncthreads();
  int kk = threadIdx.x & 63;
#pragma unroll
  for (int it = 0; it < 16; ++it) {
    int nn = rb + it * 4;
    dst[(size_t)(nrow0 + nn) * ldd + kdst0 + kk] = f2bf(tile[kk * 65 + nn]);
  }
}

// ---- GEMM1: Y[32768 x 1024] = Xbf @ WbigT^T, 128x128 tile, BK=64, bf16 out.
// XCD-aware swizzle: xcd = b&7 owns m-tiles [xcd*32, xcd*32+32); its 8 n-tiles are
// consecutive in dispatch order -> A panel stays L2-resident per XCD.
__global__ __launch_bounds__(256)
void diagcn_gemm1(const unsigned short* __restrict__ A, const unsigned short* __restrict__ BT,
                  unsigned short* __restrict__ Y) {
  const int K = 1024;
  __shared__ unsigned short As[128 * 64];
  __shared__ unsigned short Bs[128 * 64];
  const int tid = threadIdx.x;
  const int w = tid >> 6, lane = tid & 63;
  const int wm = w >> 1, wn = w & 1;
  const int quad = lane >> 4, l15 = lane & 15;
  const int b = blockIdx.x;
  const int m0 = (((b & 7) << 5) + (b >> 6)) << 7;
  const int n0 = ((b >> 3) & 7) << 7;
  const int rowg = lane >> 3;
  const int kbsw = (lane & 7) ^ rowg;

  f32x4 acc[4][4] = {};
  const unsigned short* Abase = A + (size_t)m0 * K + kbsw * 8;
  const unsigned short* Bbase = BT + (size_t)n0 * K + kbsw * 8;

  for (int k0 = 0; k0 < K; k0 += 64) {
#pragma unroll
    for (int t = 0; t < 4; ++t) {
      int grp = w * 4 + t;
      int rl = grp * 8 + rowg;
      ld_lds16(Abase + (size_t)rl * K + k0, &As[grp * 512]);
      ld_lds16(Bbase + (size_t)rl * K + k0, &Bs[grp * 512]);
    }
    __syncthreads();
#pragma unroll
    for (int ks = 0; ks < 2; ++ks) {
      bf16x8 av[4], bv[4];
      int kb = ks * 4 + quad;
#pragma unroll
      for (int i = 0; i < 4; ++i) {
        int ra = wm * 64 + i * 16 + l15;
        int rb2 = wn * 64 + i * 16 + l15;
        av[i] = *(const bf16x8*)&As[ra * 64 + ((kb ^ (ra & 7)) << 3)];
        bv[i] = *(const bf16x8*)&Bs[rb2 * 64 + ((kb ^ (rb2 & 7)) << 3)];
      }
#pragma unroll
      for (int i = 0; i < 4; ++i)
#pragma unroll
        for (int j = 0; j < 4; ++j)
          acc[i][j] = __builtin_amdgcn_mfma_f32_16x16x32_bf16(av[i], bv[j], acc[i][j], 0, 0, 0);
    }
    __syncthreads();
  }
#pragma unroll
  for (int i = 0; i < 4; ++i)
#pragma unroll
    for (int j = 0; j < 4; ++j) {
      int row = m0 + wm * 64 + i * 16 + quad * 4;
      int col = n0 + wn * 64 + j * 16 + l15;
#pragma unroll
      for (int r = 0; r < 4; ++r)
        Y[(size_t)(row + r) * 1024 + col] = f2bf(acc[i][j][r]);
    }
}

// ---- fused RGCN aggregate + GraphConv neighbor sum, one kernel.
// 2048 blocks, 16 owned nodes each (+4 halo each side -> 24 h rows in 12KB LDS).
// Phase 1 (branchless, 3 units/thread): h -> LDS (+A2[:,0:256] for owned rows).
// Phase 2 (2 units/thread): 9-tap window sum of LDS h -> A2[:,256:512].
__global__ __launch_bounds__(256)
void diagcn_hn(const unsigned short* __restrict__ Y, const int* __restrict__ spk,
               const float* __restrict__ brgcn, unsigned short* __restrict__ A2) {
  __shared__ unsigned short hl[24 * 256];
  const int b = blockIdx.x;
  const int nb = ((b & 7) << 12) + ((b >> 3) << 4);   // first owned node (XCD slab)
  const int p0 = nb & 255, dbase = nb - p0;
  const int tid = threadIdx.x;
#pragma unroll
  for (int it = 0; it < 3; ++it) {       // phase 1: h for p in [p0-4, p0+20)
    int u = tid + it * 256;
    int r = u >> 5, cb = u & 31, c0 = cb << 3;
    int p = p0 - 4 + r;
    int pc = p < 0 ? 0 : (p > 255 ? 255 : p);
    int node = dbase + pc;
    int si = spk[node];
    float a0[8] = {}, a1[8] = {};
    float n0 = 0.f, n1 = 0.f;
#pragma unroll
    for (int d = -4; d <= 4; ++d) {
      int pj = p + d;
      float w = (pj >= 0 && pj < 256) ? 1.f : 0.f;
      int jc = pj < 0 ? 0 : (pj > 255 ? 255 : pj);
      int nj = dbase + jc;
      int rel = si & spk[nj];
      u16x8 v = *(const u16x8*)&Y[(size_t)nj * 1024 + (rel << 8) + c0];
      float w1 = rel ? w : 0.f, w0 = rel ? 0.f : w;
#pragma unroll
      for (int k = 0; k < 8; ++k) {
        float f = bf2f(v[k]);
        a0[k] += f * w0; a1[k] += f * w1;
      }
      n0 += w0; n1 += w1;
    }
    u16x8 vr = *(const u16x8*)&Y[(size_t)node * 1024 + 512 + c0];
    float i0 = 1.f / fmaxf(n0, 1.f), i1 = 1.f / fmaxf(n1, 1.f);
    u16x8 uo;
#pragma unroll
    for (int k = 0; k < 8; ++k)
      uo[k] = f2bf(bf2f(vr[k]) + brgcn[c0 + k] + a0[k] * i0 + a1[k] * i1);
    *(u16x8*)&hl[r * 256 + c0] = uo;
    if (r >= 4 && r < 20)                // owned row (p always valid there)
      *(u16x8*)&A2[(size_t)(dbase + p) * 512 + c0] = uo;
  }
  __syncthreads();
#pragma unroll
  for (int it = 0; it < 2; ++it) {       // phase 2: neighbor sums for owned rows
    int u = tid + it * 256;
    int r = u >> 5, cb = u & 31, c0 = cb << 3;
    int p = p0 + r;
    float s[8] = {};
#pragma unroll
    for (int d = -4; d <= 4; ++d) {
      int pj = p + d;
      float w = (pj >= 0 && pj < 256) ? 1.f : 0.f;
      u16x8 v = *(const u16x8*)&hl[(r + 4 + d) * 256 + c0];
#pragma unroll
      for (int k = 0; k < 8; ++k) s[k] += bf2f(v[k]) * w;
    }
    u16x8 uo;
#pragma unroll
    for (int k = 0; k < 8; ++k) uo[k] = f2bf(s[k]);
    *(u16x8*)&A2[(size_t)(nb + r) * 512 + 256 + c0] = uo;
  }
}

// ---- GEMM2 + fused epilogue. 64x256 tile (full H per block), K=512.
// z = A2 @ WsmT^T + brel + bskip + Yskip; then out = z @ Wcls + bcls, log-softmax,
// per-row CE loss atomically accumulated. Yskip staged to LDS (coalesced).
__global__ __launch_bounds__(256)
void diagcn_gemm2(const unsigned short* __restrict__ A, const unsigned short* __restrict__ BT,
                  const unsigned short* __restrict__ Y, const float* __restrict__ Wcls,
                  const float* __restrict__ bcls, const float* __restrict__ brel,
                  const float* __restrict__ bskip, const int* __restrict__ labels,
                  float* __restrict__ out, float* __restrict__ loss) {
  const int K = 512;
  __shared__ unsigned short As[64 * 64];
  __shared__ unsigned short Bs[256 * 64];   // K-loop staging; reused as Yskip tile after
  __shared__ float Wc[2312];   // [0,1792) Wcls | [1792,1799) bcls | [1800,2056) brel | [2056,2312) bskip
  for (int i = threadIdx.x; i < 2312; i += 256) {
    float v;
    if (i < 1792) v = Wcls[i];
    else if (i < 1799) v = bcls[i - 1792];
    else if (i < 1800) v = 0.f;
    else if (i < 2056) v = brel[i - 1800];
    else v = bskip[i - 2056];
    Wc[i] = v;
  }
  const int tid = threadIdx.x;
  const int w = tid >> 6, lane = tid & 63;
  const int quad = lane >> 4, l15 = lane & 15;
  const int b = blockIdx.x;
  const int m0 = (((b & 7) << 6) + (b >> 3)) << 6;   // 512 m-tiles of 64 rows
  const int rowg = lane >> 3;
  const int kbsw = (lane & 7) ^ rowg;

  f32x4 acc[16] = {};
  const unsigned short* Abase = A + (size_t)m0 * K + kbsw * 8;
  const unsigned short* Bbase = BT + kbsw * 8;

  for (int k0 = 0; k0 < K; k0 += 64) {
#pragma unroll
    for (int t = 0; t < 2; ++t) {      // A: 8 groups of 8 rows
      int grp = w * 2 + t;
      ld_lds16(Abase + (size_t)(grp * 8 + rowg) * K + k0, &As[grp * 512]);
    }
#pragma unroll
    for (int t = 0; t < 8; ++t) {      // B: 32 groups of 8 rows
      int grp = w * 8 + t;
      ld_lds16(Bbase + (size_t)(grp * 8 + rowg) * K + k0, &Bs[grp * 512]);
    }
    __syncthreads();
#pragma unroll
    for (int ks = 0; ks < 2; ++ks) {
      int kb = ks * 4 + quad;
      int ra = w * 16 + l15;
      bf16x8 av = *(const bf16x8*)&As[ra * 64 + ((kb ^ (ra & 7)) << 3)];
#pragma unroll
      for (int j = 0; j < 16; ++j) {
        int rb2 = j * 16 + l15;
        bf16x8 bv = *(const bf16x8*)&Bs[rb2 * 64 + ((kb ^ (rb2 & 7)) << 3)];
        acc[j] = __builtin_amdgcn_mfma_f32_16x16x32_bf16(av, bv, acc[j], 0, 0, 0);
      }
    }
    __syncthreads();
  }

  // stage Yskip tile (64 rows x 256 cols bf16 = 32KB) into Bs, coalesced
  unsigned short* Ysk = Bs;
  {
    int row2 = w * 2 + (lane >> 5);
    const unsigned short* ysrc = Y + (size_t)(m0 + row2) * 1024 + 768 + (lane & 31) * 8;
#pragma unroll
    for (int pS = 0; pS < 8; ++pS)
      ld_lds16(ysrc + (size_t)pS * 8 * 1024, &Ysk[(pS * 8 + w * 2) * 256]);
  }
  __syncthreads();

  // ---- epilogue: bias + skip, classifier partials
  float wsum[4][7] = {};
#pragma unroll
  for (int j = 0; j < 16; ++j) {
    int col = j * 16 + l15;
    float bb = Wc[1800 + col] + Wc[2056 + col];
#pragma unroll
    for (int r = 0; r < 4; ++r) {
      int lrow = w * 16 + quad * 4 + r;
      float z = acc[j][r] + bb + bf2f(Ysk[lrow * 256 + col]);
#pragma unroll
      for (int c = 0; c < 7; ++c) wsum[r][c] += z * Wc[col * 7 + c];
    }
  }
#pragma unroll
  for (int o = 1; o < 16; o <<= 1)
#pragma unroll
    for (int r = 0; r < 4; ++r)
#pragma unroll
      for (int c = 0; c < 7; ++c) wsum[r][c] += __shfl_xor(wsum[r][c], o, 64);

  float lsum = 0.f;
#pragma unroll
  for (int r = 0; r < 4; ++r) {
    int row = m0 + w * 16 + quad * 4 + r;
    float o7[7], mx = -1e30f;
#pragma unroll
    for (int c = 0; c < 7; ++c) {
      o7[c] = wsum[r][c] + Wc[1792 + c];
      mx = fmaxf(mx, o7[c]);
    }
    if (l15 < 7) out[(size_t)row * 7 + l15] = o7[l15];
    float s = 0.f;
#pragma unroll
    for (int c = 0; c < 7; ++c) s += expf(o7[c] - mx);
    int lab = labels[row];
    lsum += mx + logf(s) - o7[lab];
  }
  lsum += __shfl_xor(lsum, 16, 64);
  lsum += __shfl_xor(lsum, 32, 64);
  if (lane == 0) atomicAdd(loss, lsum * (1.0f / (float)NN));
}

extern "C" void kernel_launch(void* const* d_in, const int* in_sizes, int n_in,
                              void* d_out, int out_size, void* d_ws, size_t ws_size,
                              hipStream_t stream) {
  const float* x      = (const float*)d_in[0];
  const int* speakers = (const int*)d_in[2];
  const int* labels   = (const int*)d_in[3];
  const float* Wrgcn  = (const float*)d_in[6];
  const float* Wroot  = (const float*)d_in[7];
  const float* brgcn  = (const float*)d_in[8];
  const float* Wrel   = (const float*)d_in[9];
  const float* brel   = (const float*)d_in[10];
  const float* Wgrt   = (const float*)d_in[11];
  const float* Wskip  = (const float*)d_in[12];
  const float* bskip  = (const float*)d_in[13];
  const float* Wcls   = (const float*)d_in[14];
  const float* bcls   = (const float*)d_in[15];
  float* out = (float*)d_out;
  float* loss = out + (size_t)NN * 7;

  // workspace layout (bytes)
  const size_t OFF_XBF  = 0;                  // 67,108,864  (bf16 X)
  const size_t OFF_WBIG = 67108864;           //  2,097,152
  const size_t OFF_WSM  = 69206016;           //    262,144
  const size_t OFF_Y    = 69468160;           // 67,108,864  (bf16 [Y0|Y1|Yroot|Yskip])
  const size_t OFF_A2   = 136577024;          // 33,554,432  (bf16 [h|neigh])
  const size_t NEED     = 170131456;
  if (ws_size < NEED) return;

  char* ws = (char*)d_ws;
  unsigned short* Xbf   = (unsigned short*)(ws + OFF_XBF);
  unsigned short* WbigT = (unsigned short*)(ws + OFF_WBIG);
  unsigned short* WsmT  = (unsigned short*)(ws + OFF_WSM);
  unsigned short* Y     = (unsigned short*)(ws + OFF_Y);
  unsigned short* A2    = (unsigned short*)(ws + OFF_A2);

  diagcn_prep<<<dim3(2336), dim3(256), 0, stream>>>(x, Wrgcn, Wroot, Wskip, Wgrt, Wrel,
                                                    Xbf, WbigT, WsmT, loss);
  diagcn_gemm1<<<dim3(2048), dim3(256), 0, stream>>>(Xbf, WbigT, Y);
  diagcn_hn<<<dim3(2048), dim3(256), 0, stream>>>(Y, speakers, brgcn, A2);
  diagcn_gemm2<<<dim3(512), dim3(256), 0, stream>>>(A2, WsmT, Y, Wcls, bcls, brel, bskip,
                                                    labels, out, loss);
}

// Round 7
// 388.247 us; speedup vs baseline: 1.0154x; 1.0154x over previous
//
#include <hip/hip_runtime.h>

// Problem constants (fixed by reference): B=128, L=256, F=P=4, IN=1024, H=256, C=7
#define NN 32768        // N = B*L
#define INF 1024
#define HF 256

typedef __bf16 bf16x8 __attribute__((ext_vector_type(8)));
typedef float f32x4 __attribute__((ext_vector_type(4)));
typedef unsigned short u16x8 __attribute__((ext_vector_type(8)));

__device__ __forceinline__ float bf2f(unsigned short u) {
  union { unsigned int i; float f; } v; v.i = ((unsigned int)u) << 16; return v.f;
}
__device__ __forceinline__ unsigned short f2bf(float f) {
  union { float f; unsigned int i; } v; v.f = f;
  unsigned int x = v.i;
  return (unsigned short)((x + 0x7fffu + ((x >> 16) & 1u)) >> 16);  // RNE
}

// async global->LDS, 16B per lane; dest = lds base (wave-uniform) + lane*16
__device__ __forceinline__ void ld_lds16(const unsigned short* g, unsigned short* l) {
  __builtin_amdgcn_global_load_lds(
      (__attribute__((address_space(1))) const unsigned int*)g,
      (__attribute__((address_space(3))) unsigned int*)l, 16, 0, 0);
}

// ---- prep:
//  blocks [0,288):    weight repack via 64x64 LDS transpose (coalesced both sides)
//  blocks [288,8480): x fp32 -> bf16; 4 independent float4 loads batched per thread
//                     (MLP: all 4 issued before first use; r5/r6's 16-deep serial
//                     grid-stride at VGPR=28 was latency-bound at 1.6 TB/s)
// WbigT[n][k] (1024x1024) = [W0|W1|Wroot|Wskip]^T ; WsmT[n][k] (256x512) = [Wgrt;Wrel]^T
__global__ __launch_bounds__(256)
void diagcn_prep(const float* __restrict__ x, const float* __restrict__ Wrgcn,
                 const float* __restrict__ Wroot, const float* __restrict__ Wskip,
                 const float* __restrict__ Wgrt, const float* __restrict__ Wrel,
                 unsigned short* __restrict__ Xbf, unsigned short* __restrict__ WbigT,
                 unsigned short* __restrict__ WsmT, float* __restrict__ loss) {
  int bid = blockIdx.x;
  if (bid >= 288) {
    if (bid == 288 && threadIdx.x == 0) loss[0] = 0.f;
    int base = (bid - 288) * 1024 + threadIdx.x;   // 4 float4 chunks of 256 threads
    const float4* x4 = (const float4*)x;
    float4 v0 = x4[base];
    float4 v1 = x4[base + 256];
    float4 v2 = x4[base + 512];
    float4 v3 = x4[base + 768];
    ushort4 u0, u1, u2, u3;
    u0.x = f2bf(v0.x); u0.y = f2bf(v0.y); u0.z = f2bf(v0.z); u0.w = f2bf(v0.w);
    u1.x = f2bf(v1.x); u1.y = f2bf(v1.y); u1.z = f2bf(v1.z); u1.w = f2bf(v1.w);
    u2.x = f2bf(v2.x); u2.y = f2bf(v2.y); u2.z = f2bf(v2.z); u2.w = f2bf(v2.w);
    u3.x = f2bf(v3.x); u3.y = f2bf(v3.y); u3.z = f2bf(v3.z); u3.w = f2bf(v3.w);
    ushort4* o4 = (ushort4*)Xbf;
    o4[base] = u0;
    o4[base + 256] = u1;
    o4[base + 512] = u2;
    o4[base + 768] = u3;
    return;
  }
  __shared__ float tile[64 * 65];
  int tb = bid;
  const float* src;
  int k0, ncol0;
  unsigned short* dst;
  int ldd, nrow0;
  if (tb < 256) {            // WbigT tiles: tn 0..15, tk 0..15
    int tn = tb >> 4, tk = tb & 15;
    int mat = tn >> 2;
    src = (mat == 0) ? Wrgcn : (mat == 1) ? (Wrgcn + 262144) : (mat == 2) ? Wroot : Wskip;
    k0 = tk * 64; ncol0 = (tn & 3) * 64;
    dst = WbigT; ldd = 1024; nrow0 = tn * 64;
  } else {                   // WsmT tiles: tn 0..3, tk 0..7
    int t2 = tb - 256;
    int tn = t2 >> 3, tk = t2 & 7;
    src = (tk < 4) ? Wgrt : Wrel;
    k0 = (tk & 3) * 64; ncol0 = tn * 64;
    dst = WsmT; ldd = 512; nrow0 = tn * 64;
  }
  int kdst0 = (tb < 256) ? k0 : (((tb - 256) & 7) * 64);
  int c = threadIdx.x & 63, rb = threadIdx.x >> 6;
#pragma unroll
  for (int it = 0; it < 16; ++it) {
    int r = rb + it * 4;
    tile[r * 65 + c] = src[(size_t)(k0 + r) * 256 + ncol0 + c];
  }
  __syncthreads();
  int kk = threadIdx.x & 63;
#pragma unroll
  for (int it = 0; it < 16; ++it) {
    int nn = rb + it * 4;
    dst[(size_t)(nrow0 + nn) * ldd + kdst0 + kk] = f2bf(tile[kk * 65 + nn]);
  }
}

// ---- GEMM1: Y[32768 x 1024] = Xbf @ WbigT^T, 128x128 tile, BK=64, bf16 out.
// XCD-aware swizzle: xcd = b&7 owns m-tiles [xcd*32, xcd*32+32); its 8 n-tiles are
// consecutive in dispatch order -> A panel stays L2-resident per XCD.
__global__ __launch_bounds__(256)
void diagcn_gemm1(const unsigned short* __restrict__ A, const unsigned short* __restrict__ BT,
                  unsigned short* __restrict__ Y) {
  const int K = 1024;
  __shared__ unsigned short As[128 * 64];
  __shared__ unsigned short Bs[128 * 64];
  const int tid = threadIdx.x;
  const int w = tid >> 6, lane = tid & 63;
  const int wm = w >> 1, wn = w & 1;
  const int quad = lane >> 4, l15 = lane & 15;
  const int b = blockIdx.x;
  const int m0 = (((b & 7) << 5) + (b >> 6)) << 7;
  const int n0 = ((b >> 3) & 7) << 7;
  const int rowg = lane >> 3;
  const int kbsw = (lane & 7) ^ rowg;

  f32x4 acc[4][4] = {};
  const unsigned short* Abase = A + (size_t)m0 * K + kbsw * 8;
  const unsigned short* Bbase = BT + (size_t)n0 * K + kbsw * 8;

  for (int k0 = 0; k0 < K; k0 += 64) {
#pragma unroll
    for (int t = 0; t < 4; ++t) {
      int grp = w * 4 + t;
      int rl = grp * 8 + rowg;
      ld_lds16(Abase + (size_t)rl * K + k0, &As[grp * 512]);
      ld_lds16(Bbase + (size_t)rl * K + k0, &Bs[grp * 512]);
    }
    __syncthreads();
#pragma unroll
    for (int ks = 0; ks < 2; ++ks) {
      bf16x8 av[4], bv[4];
      int kb = ks * 4 + quad;
#pragma unroll
      for (int i = 0; i < 4; ++i) {
        int ra = wm * 64 + i * 16 + l15;
        int rb2 = wn * 64 + i * 16 + l15;
        av[i] = *(const bf16x8*)&As[ra * 64 + ((kb ^ (ra & 7)) << 3)];
        bv[i] = *(const bf16x8*)&Bs[rb2 * 64 + ((kb ^ (rb2 & 7)) << 3)];
      }
#pragma unroll
      for (int i = 0; i < 4; ++i)
#pragma unroll
        for (int j = 0; j < 4; ++j)
          acc[i][j] = __builtin_amdgcn_mfma_f32_16x16x32_bf16(av[i], bv[j], acc[i][j], 0, 0, 0);
    }
    __syncthreads();
  }
#pragma unroll
  for (int i = 0; i < 4; ++i)
#pragma unroll
    for (int j = 0; j < 4; ++j) {
      int row = m0 + wm * 64 + i * 16 + quad * 4;
      int col = n0 + wn * 64 + j * 16 + l15;
#pragma unroll
      for (int r = 0; r < 4; ++r)
        Y[(size_t)(row + r) * 1024 + col] = f2bf(acc[i][j][r]);
    }
}

// ---- fused RGCN aggregate + GraphConv neighbor sum, one kernel.
// 2048 blocks, 16 owned nodes each (+4 halo each side -> 24 h rows in 12KB LDS).
// Phase 1 (branchless, 3 units/thread): h -> LDS (+A2[:,0:256] for owned rows).
// Phase 2 (2 units/thread): 9-tap window sum of LDS h -> A2[:,256:512].
__global__ __launch_bounds__(256)
void diagcn_hn(const unsigned short* __restrict__ Y, const int* __restrict__ spk,
               const float* __restrict__ brgcn, unsigned short* __restrict__ A2) {
  __shared__ unsigned short hl[24 * 256];
  const int b = blockIdx.x;
  const int nb = ((b & 7) << 12) + ((b >> 3) << 4);   // first owned node (XCD slab)
  const int p0 = nb & 255, dbase = nb - p0;
  const int tid = threadIdx.x;
#pragma unroll
  for (int it = 0; it < 3; ++it) {       // phase 1: h for p in [p0-4, p0+20)
    int u = tid + it * 256;
    int r = u >> 5, cb = u & 31, c0 = cb << 3;
    int p = p0 - 4 + r;
    int pc = p < 0 ? 0 : (p > 255 ? 255 : p);
    int node = dbase + pc;
    int si = spk[node];
    float a0[8] = {}, a1[8] = {};
    float n0 = 0.f, n1 = 0.f;
#pragma unroll
    for (int d = -4; d <= 4; ++d) {
      int pj = p + d;
      float w = (pj >= 0 && pj < 256) ? 1.f : 0.f;
      int jc = pj < 0 ? 0 : (pj > 255 ? 255 : pj);
      int nj = dbase + jc;
      int rel = si & spk[nj];
      u16x8 v = *(const u16x8*)&Y[(size_t)nj * 1024 + (rel << 8) + c0];
      float w1 = rel ? w : 0.f, w0 = rel ? 0.f : w;
#pragma unroll
      for (int k = 0; k < 8; ++k) {
        float f = bf2f(v[k]);
        a0[k] += f * w0; a1[k] += f * w1;
      }
      n0 += w0; n1 += w1;
    }
    u16x8 vr = *(const u16x8*)&Y[(size_t)node * 1024 + 512 + c0];
    float i0 = 1.f / fmaxf(n0, 1.f), i1 = 1.f / fmaxf(n1, 1.f);
    u16x8 uo;
#pragma unroll
    for (int k = 0; k < 8; ++k)
      uo[k] = f2bf(bf2f(vr[k]) + brgcn[c0 + k] + a0[k] * i0 + a1[k] * i1);
    *(u16x8*)&hl[r * 256 + c0] = uo;
    if (r >= 4 && r < 20)                // owned row (p always valid there)
      *(u16x8*)&A2[(size_t)(dbase + p) * 512 + c0] = uo;
  }
  __syncthreads();
#pragma unroll
  for (int it = 0; it < 2; ++it) {       // phase 2: neighbor sums for owned rows
    int u = tid + it * 256;
    int r = u >> 5, cb = u & 31, c0 = cb << 3;
    int p = p0 + r;
    float s[8] = {};
#pragma unroll
    for (int d = -4; d <= 4; ++d) {
      int pj = p + d;
      float w = (pj >= 0 && pj < 256) ? 1.f : 0.f;
      u16x8 v = *(const u16x8*)&hl[(r + 4 + d) * 256 + c0];
#pragma unroll
      for (int k = 0; k < 8; ++k) s[k] += bf2f(v[k]) * w;
    }
    u16x8 uo;
#pragma unroll
    for (int k = 0; k < 8; ++k) uo[k] = f2bf(s[k]);
    *(u16x8*)&A2[(size_t)(nb + r) * 512 + 256 + c0] = uo;
  }
}

// ---- GEMM2 + fused epilogue. 64x256 tile (full H per block), K=512.
// z = A2 @ WsmT^T + brel + bskip + Yskip; then out = z @ Wcls + bcls, log-softmax,
// per-row CE loss atomically accumulated. Yskip staged to LDS (coalesced).
__global__ __launch_bounds__(256)
void diagcn_gemm2(const unsigned short* __restrict__ A, const unsigned short* __restrict__ BT,
                  const unsigned short* __restrict__ Y, const float* __restrict__ Wcls,
                  const float* __restrict__ bcls, const float* __restrict__ brel,
                  const float* __restrict__ bskip, const int* __restrict__ labels,
                  float* __restrict__ out, float* __restrict__ loss) {
  const int K = 512;
  __shared__ unsigned short As[64 * 64];
  __shared__ unsigned short Bs[256 * 64];   // K-loop staging; reused as Yskip tile after
  __shared__ float Wc[2312];   // [0,1792) Wcls | [1792,1799) bcls | [1800,2056) brel | [2056,2312) bskip
  for (int i = threadIdx.x; i < 2312; i += 256) {
    float v;
    if (i < 1792) v = Wcls[i];
    else if (i < 1799) v = bcls[i - 1792];
    else if (i < 1800) v = 0.f;
    else if (i < 2056) v = brel[i - 1800];
    else v = bskip[i - 2056];
    Wc[i] = v;
  }
  const int tid = threadIdx.x;
  const int w = tid >> 6, lane = tid & 63;
  const int quad = lane >> 4, l15 = lane & 15;
  const int b = blockIdx.x;
  const int m0 = (((b & 7) << 6) + (b >> 3)) << 6;   // 512 m-tiles of 64 rows
  const int rowg = lane >> 3;
  const int kbsw = (lane & 7) ^ rowg;

  f32x4 acc[16] = {};
  const unsigned short* Abase = A + (size_t)m0 * K + kbsw * 8;
  const unsigned short* Bbase = BT + kbsw * 8;

  for (int k0 = 0; k0 < K; k0 += 64) {
#pragma unroll
    for (int t = 0; t < 2; ++t) {      // A: 8 groups of 8 rows
      int grp = w * 2 + t;
      ld_lds16(Abase + (size_t)(grp * 8 + rowg) * K + k0, &As[grp * 512]);
    }
#pragma unroll
    for (int t = 0; t < 8; ++t) {      // B: 32 groups of 8 rows
      int grp = w * 8 + t;
      ld_lds16(Bbase + (size_t)(grp * 8 + rowg) * K + k0, &Bs[grp * 512]);
    }
    __syncthreads();
#pragma unroll
    for (int ks = 0; ks < 2; ++ks) {
      int kb = ks * 4 + quad;
      int ra = w * 16 + l15;
      bf16x8 av = *(const bf16x8*)&As[ra * 64 + ((kb ^ (ra & 7)) << 3)];
#pragma unroll
      for (int j = 0; j < 16; ++j) {
        int rb2 = j * 16 + l15;
        bf16x8 bv = *(const bf16x8*)&Bs[rb2 * 64 + ((kb ^ (rb2 & 7)) << 3)];
        acc[j] = __builtin_amdgcn_mfma_f32_16x16x32_bf16(av, bv, acc[j], 0, 0, 0);
      }
    }
    __syncthreads();
  }

  // stage Yskip tile (64 rows x 256 cols bf16 = 32KB) into Bs, coalesced
  unsigned short* Ysk = Bs;
  {
    int row2 = w * 2 + (lane >> 5);
    const unsigned short* ysrc = Y + (size_t)(m0 + row2) * 1024 + 768 + (lane & 31) * 8;
#pragma unroll
    for (int pS = 0; pS < 8; ++pS)
      ld_lds16(ysrc + (size_t)pS * 8 * 1024, &Ysk[(pS * 8 + w * 2) * 256]);
  }
  __syncthreads();

  // ---- epilogue: bias + skip, classifier partials
  float wsum[4][7] = {};
#pragma unroll
  for (int j = 0; j < 16; ++j) {
    int col = j * 16 + l15;
    float bb = Wc[1800 + col] + Wc[2056 + col];
#pragma unroll
    for (int r = 0; r < 4; ++r) {
      int lrow = w * 16 + quad * 4 + r;
      float z = acc[j][r] + bb + bf2f(Ysk[lrow * 256 + col]);
#pragma unroll
      for (int c = 0; c < 7; ++c) wsum[r][c] += z * Wc[col * 7 + c];
    }
  }
#pragma unroll
  for (int o = 1; o < 16; o <<= 1)
#pragma unroll
    for (int r = 0; r < 4; ++r)
#pragma unroll
      for (int c = 0; c < 7; ++c) wsum[r][c] += __shfl_xor(wsum[r][c], o, 64);

  float lsum = 0.f;
#pragma unroll
  for (int r = 0; r < 4; ++r) {
    int row = m0 + w * 16 + quad * 4 + r;
    float o7[7], mx = -1e30f;
#pragma unroll
    for (int c = 0; c < 7; ++c) {
      o7[c] = wsum[r][c] + Wc[1792 + c];
      mx = fmaxf(mx, o7[c]);
    }
    if (l15 < 7) out[(size_t)row * 7 + l15] = o7[l15];
    float s = 0.f;
#pragma unroll
    for (int c = 0; c < 7; ++c) s += expf(o7[c] - mx);
    int lab = labels[row];
    lsum += mx + logf(s) - o7[lab];
  }
  lsum += __shfl_xor(lsum, 16, 64);
  lsum += __shfl_xor(lsum, 32, 64);
  if (lane == 0) atomicAdd(loss, lsum * (1.0f / (float)NN));
}

extern "C" void kernel_launch(void* const* d_in, const int* in_sizes, int n_in,
                              void* d_out, int out_size, void* d_ws, size_t ws_size,
                              hipStream_t stream) {
  const float* x      = (const float*)d_in[0];
  const int* speakers = (const int*)d_in[2];
  const int* labels   = (const int*)d_in[3];
  const float* Wrgcn  = (const float*)d_in[6];
  const float* Wroot  = (const float*)d_in[7];
  const float* brgcn  = (const float*)d_in[8];
  const float* Wrel   = (const float*)d_in[9];
  const float* brel   = (const float*)d_in[10];
  const float* Wgrt   = (const float*)d_in[11];
  const float* Wskip  = (const float*)d_in[12];
  const float* bskip  = (const float*)d_in[13];
  const float* Wcls   = (const float*)d_in[14];
  const float* bcls   = (const float*)d_in[15];
  float* out = (float*)d_out;
  float* loss = out + (size_t)NN * 7;

  // workspace layout (bytes)
  const size_t OFF_XBF  = 0;                  // 67,108,864  (bf16 X)
  const size_t OFF_WBIG = 67108864;           //  2,097,152
  const size_t OFF_WSM  = 69206016;           //    262,144
  const size_t OFF_Y    = 69468160;           // 67,108,864  (bf16 [Y0|Y1|Yroot|Yskip])
  const size_t OFF_A2   = 136577024;          // 33,554,432  (bf16 [h|neigh])
  const size_t NEED     = 170131456;
  if (ws_size < NEED) return;

  char* ws = (char*)d_ws;
  unsigned short* Xbf   = (unsigned short*)(ws + OFF_XBF);
  unsigned short* WbigT = (unsigned short*)(ws + OFF_WBIG);
  unsigned short* WsmT  = (unsigned short*)(ws + OFF_WSM);
  unsigned short* Y     = (unsigned short*)(ws + OFF_Y);
  unsigned short* A2    = (unsigned short*)(ws + OFF_A2);

  diagcn_prep<<<dim3(8480), dim3(256), 0, stream>>>(x, Wrgcn, Wroot, Wskip, Wgrt, Wrel,
                                                    Xbf, WbigT, WsmT, loss);
  diagcn_gemm1<<<dim3(2048), dim3(256), 0, stream>>>(Xbf, WbigT, Y);
  diagcn_hn<<<dim3(2048), dim3(256), 0, stream>>>(Y, speakers, brgcn, A2);
  diagcn_gemm2<<<dim3(512), dim3(256), 0, stream>>>(A2, WsmT, Y, Wcls, bcls, brel, bskip,
                                                    labels, out, loss);
}